// Round 11
// baseline (182.423 us; speedup 1.0000x reference)
//
#include <hip/hip_runtime.h>
#include <math.h>

#define BB 32
#define LL 256
#define DD 16
#define HH 64
#define KK 5
#define TT 252          // LL - KK + 1
#define PP 126          // TT/2
#define SS 8064         // HH*PP
#define NCHUNK 63
#define CHUNK 128       // 63*128 = 8064
#define NCB 8           // 8 * 256 thr * 4 cols = 8192 >= 8064

// ---------------- kernel 12: conv + relu + recon + pool (fused per (b,d)) --
__global__ __launch_bounds__(256) void k12_conv_recon(
    const float* __restrict__ x, const float* __restrict__ cw,
    const float* __restrict__ cb, const float* __restrict__ dw,
    const float* __restrict__ db, float* __restrict__ flat,
    float* __restrict__ mainT, float* __restrict__ recon) {
  __shared__ float ylds[HH * TT];   // 64*252 = 16128 f = 64512 B
  __shared__ float xs[LL];
  __shared__ float cws[HH * KK];
  __shared__ float dws[HH * KK];
  __shared__ float cbs[HH];

  int bd = blockIdx.x;              // b*DD + d
  int b = bd / DD, d = bd % DD;
  int tid = threadIdx.x;

  xs[tid] = x[((size_t)b * LL + tid) * DD + d];
  for (int i = tid; i < HH * KK; i += 256) {
    cws[i] = cw[(size_t)d * HH * KK + i];
    dws[i] = dw[(size_t)d * HH * KK + i];
  }
  if (tid < HH) cbs[tid] = cb[d * HH + tid];
  __syncthreads();

  {
    int h = tid >> 2, a = tid & 3;
    int t0 = a * 63;
    float w0 = cws[h * KK + 0], w1 = cws[h * KK + 1], w2 = cws[h * KK + 2],
          w3 = cws[h * KK + 3], w4 = cws[h * KK + 4];
    float bias = cbs[h];
    float x0 = xs[t0], x1 = xs[t0 + 1], x2 = xs[t0 + 2], x3 = xs[t0 + 3],
          x4 = xs[t0 + 4];
    float* yrow = ylds + h * TT + t0;
    #pragma unroll 7
    for (int t = 0; t < 63; ++t) {
      float yv = fmaf(w4, x4, fmaf(w3, x3, fmaf(w2, x2, fmaf(w1, x1, fmaf(w0, x0, bias)))));
      yrow[t] = fmaxf(yv, 0.f);
      x0 = x1; x1 = x2; x2 = x3; x3 = x4;
      if (t < 62) x4 = xs[t0 + t + 5];
    }
  }
  __syncthreads();

  for (int i = tid; i < HH * PP; i += 256) {
    int h = i / PP, p = i - h * PP;
    float pooled = 0.5f * (ylds[h * TT + 2 * p] + ylds[h * TT + 2 * p + 1]);
    flat[(size_t)bd * SS + i] = pooled;
    if (d == 0) mainT[(size_t)i * BB + b] = pooled;   // [s][b]
  }

  {
    int l = tid;
    float acc = db[d];
    for (int h = 0; h < HH; ++h) {
      const float* yl = ylds + h * TT;
      #pragma unroll
      for (int j = 0; j < KK; ++j) {
        int t = l - j;
        if (t >= 0 && t < TT) acc = fmaf(yl[t], dws[h * KK + j], acc);
      }
    }
    recon[(size_t)bd * LL + l] = acc;
  }
}

// ---------------- kernel 3: partial = main @ W_attn -------------------------
// Thread tile = 4 cols x ALL 32 batches (32 NAMED float4 accumulators).
// m chunk staged once in LDS (16 KB) -> 8 uniform ds_read_b128 per k-step on
// lgkmcnt; W = one coalesced dwordx4 per k-step on a PURE vmcnt queue with
// 4-deep rotating named prefetch. Per k-step: 9 load-instr feed 128 FMA-instr
// (256 VALU cyc) -- 4x lower load pressure than round 7.
#define FMA4V(A, WF, S)                                       \
  A.x = fmaf(WF.x, S, A.x); A.y = fmaf(WF.y, S, A.y);         \
  A.z = fmaf(WF.z, S, A.z); A.w = fmaf(WF.w, S, A.w);

#define MSTEP(WF, KI) {                                                  \
  const float* mr = mlds + (KI) * BB;                                    \
  float4 q0 = *(const float4*)(mr + 0),  q1 = *(const float4*)(mr + 4),  \
         q2 = *(const float4*)(mr + 8),  q3 = *(const float4*)(mr + 12), \
         q4 = *(const float4*)(mr + 16), q5 = *(const float4*)(mr + 20), \
         q6 = *(const float4*)(mr + 24), q7 = *(const float4*)(mr + 28); \
  FMA4V(b00, WF, q0.x) FMA4V(b01, WF, q0.y) FMA4V(b02, WF, q0.z) FMA4V(b03, WF, q0.w) \
  FMA4V(b04, WF, q1.x) FMA4V(b05, WF, q1.y) FMA4V(b06, WF, q1.z) FMA4V(b07, WF, q1.w) \
  FMA4V(b08, WF, q2.x) FMA4V(b09, WF, q2.y) FMA4V(b10, WF, q2.z) FMA4V(b11, WF, q2.w) \
  FMA4V(b12, WF, q3.x) FMA4V(b13, WF, q3.y) FMA4V(b14, WF, q3.z) FMA4V(b15, WF, q3.w) \
  FMA4V(b16, WF, q4.x) FMA4V(b17, WF, q4.y) FMA4V(b18, WF, q4.z) FMA4V(b19, WF, q4.w) \
  FMA4V(b20, WF, q5.x) FMA4V(b21, WF, q5.y) FMA4V(b22, WF, q5.z) FMA4V(b23, WF, q5.w) \
  FMA4V(b24, WF, q6.x) FMA4V(b25, WF, q6.y) FMA4V(b26, WF, q6.z) FMA4V(b27, WF, q6.w) \
  FMA4V(b28, WF, q7.x) FMA4V(b29, WF, q7.y) FMA4V(b30, WF, q7.z) FMA4V(b31, WF, q7.w) }

// consume WREG for k-step KI, then prefetch row KI+4 into WREG
#define KSTEP4(WREG, KI) {                                               \
  float4 wc = WREG;                                                      \
  if ((KI) + 4 < CHUNK)                                                  \
    WREG = *(const float4*)(wp + (size_t)((KI) + 4) * SS);               \
  MSTEP(wc, KI) }

#define STB(A, BI) *(float4*)(pp + (size_t)(BI) * SS) = A;

__global__ __launch_bounds__(256) void k3_matmul(
    const float* __restrict__ W, const float* __restrict__ mainT,
    float* __restrict__ partial) {
  __shared__ float mlds[CHUNK * BB];   // 128*32*4 = 16 KB
  int chunk = blockIdx.y;
  int s0 = chunk * CHUNK;
  int tid = threadIdx.x;

  // stage m chunk (coalesced float4 copy: 1024 f4 / 256 thr = 4 each)
  {
    const float4* src = (const float4*)(mainT + (size_t)s0 * BB);
    float4* dst = (float4*)mlds;
    #pragma unroll
    for (int i = 0; i < 4; ++i) dst[tid + i * 256] = src[tid + i * 256];
  }
  __syncthreads();

  int col = blockIdx.x * 1024 + tid * 4;     // 0..8188
  bool ok = col < SS;
  int cc = ok ? col : SS - 4;

  float4 z = make_float4(0.f, 0.f, 0.f, 0.f);
  float4 b00 = z, b01 = z, b02 = z, b03 = z, b04 = z, b05 = z, b06 = z, b07 = z;
  float4 b08 = z, b09 = z, b10 = z, b11 = z, b12 = z, b13 = z, b14 = z, b15 = z;
  float4 b16 = z, b17 = z, b18 = z, b19 = z, b20 = z, b21 = z, b22 = z, b23 = z;
  float4 b24 = z, b25 = z, b26 = z, b27 = z, b28 = z, b29 = z, b30 = z, b31 = z;

  const float* wp = W + (size_t)s0 * SS + cc;

  // 4-deep W prefetch (coalesced dwordx4 per lane; only W rides vmcnt)
  float4 wA = *(const float4*)(wp);
  float4 wB = *(const float4*)(wp + (size_t)SS);
  float4 wC = *(const float4*)(wp + 2 * (size_t)SS);
  float4 wD = *(const float4*)(wp + 3 * (size_t)SS);

  #pragma unroll 1
  for (int k = 0; k < CHUNK; k += 4) {
    KSTEP4(wA, k + 0)
    KSTEP4(wB, k + 1)
    KSTEP4(wC, k + 2)
    KSTEP4(wD, k + 3)
  }

  if (ok) {
    float* pp = partial + (size_t)chunk * BB * SS + col;
    STB(b00, 0)  STB(b01, 1)  STB(b02, 2)  STB(b03, 3)
    STB(b04, 4)  STB(b05, 5)  STB(b06, 6)  STB(b07, 7)
    STB(b08, 8)  STB(b09, 9)  STB(b10, 10) STB(b11, 11)
    STB(b12, 12) STB(b13, 13) STB(b14, 14) STB(b15, 15)
    STB(b16, 16) STB(b17, 17) STB(b18, 18) STB(b19, 19)
    STB(b20, 20) STB(b21, 21) STB(b22, 22) STB(b23, 23)
    STB(b24, 24) STB(b25, 25) STB(b26, 26) STB(b27, 27)
    STB(b28, 28) STB(b29, 29) STB(b30, 30) STB(b31, 31)
  }
}

// ---------------- kernel 3b: reduce partials -> m (float4) ------------------
__global__ __launch_bounds__(256) void k3b_reduce(
    const float4* __restrict__ partial, float4* __restrict__ m) {
  int i = blockIdx.x * 256 + threadIdx.x;      // < BB*SS/4 = 64512
  float4 s = make_float4(0.f, 0.f, 0.f, 0.f);
  for (int c = 0; c < NCHUNK; ++c) {
    float4 v = partial[(size_t)c * (BB * SS / 4) + i];
    s.x += v.x; s.y += v.y; s.z += v.z; s.w += v.w;
  }
  m[i] = s;
}

// ---------------- kernel 4: scores[b,d'] = <m[b,:], aux[b,d',:]> ------------
__global__ __launch_bounds__(256) void k4_scores(
    const float* __restrict__ m, const float* __restrict__ flat,
    float* __restrict__ scores) {
  int bd = blockIdx.x;            // b*15 + dd
  int b = bd / 15, dd = bd % 15;
  const float* mb = m + (size_t)b * SS;
  const float* ab = flat + ((size_t)b * DD + 1 + dd) * SS;
  float p = 0.f;
  for (int s = threadIdx.x; s < SS; s += 256) p = fmaf(mb[s], ab[s], p);
  #pragma unroll
  for (int o = 32; o; o >>= 1) p += __shfl_xor(p, o);
  __shared__ float red[4];
  if ((threadIdx.x & 63) == 0) red[threadIdx.x >> 6] = p;
  __syncthreads();
  if (threadIdx.x == 0) scores[bd] = red[0] + red[1] + red[2] + red[3];
}

// ---------------- kernel 5: softmax over 15 ---------------------------------
__global__ __launch_bounds__(64) void k5_softmax(
    const float* __restrict__ scores, float* __restrict__ attn_out) {
  int b = blockIdx.x;
  int lane = threadIdx.x;
  float v = (lane < 15) ? scores[b * 15 + lane] : -INFINITY;
  float mx = v;
  #pragma unroll
  for (int o = 32; o; o >>= 1) mx = fmaxf(mx, __shfl_xor(mx, o));
  float e = (lane < 15) ? expf(v - mx) : 0.f;
  float sum = e;
  #pragma unroll
  for (int o = 32; o; o >>= 1) sum += __shfl_xor(sum, o);
  if (lane < 15) attn_out[b * 15 + lane] = e / sum;
}

// ---------------- kernel 6: main copy + weighted sum ------------------------
__global__ __launch_bounds__(256) void k6_out(
    const float* __restrict__ flat, const float* __restrict__ attn,
    float* __restrict__ out) {
  int b = blockIdx.y;
  int s = blockIdx.x * 256 + threadIdx.x;
  if (s >= SS) return;
  const float* fb = flat + (size_t)b * DD * SS;
  out[(size_t)b * 2 * SS + s] = fb[s];
  float w = 0.f;
  #pragma unroll
  for (int d = 0; d < 15; ++d)
    w = fmaf(attn[b * 15 + d], fb[(size_t)(1 + d) * SS + s], w);
  out[(size_t)b * 2 * SS + SS + s] = w;
}

// ---------------------------------------------------------------------------
extern "C" void kernel_launch(void* const* d_in, const int* in_sizes, int n_in,
                              void* d_out, int out_size, void* d_ws, size_t ws_size,
                              hipStream_t stream) {
  const float* x        = (const float*)d_in[0];
  const float* conv_w   = (const float*)d_in[1];
  const float* conv_b   = (const float*)d_in[2];
  const float* deconv_w = (const float*)d_in[3];
  const float* deconv_b = (const float*)d_in[4];
  const float* W_attn   = (const float*)d_in[5];
  float* out = (float*)d_out;

  // output layout: [ out (516096) | attn (480) | recon (131072) ]
  const size_t ATTN_OFF  = (size_t)BB * 2 * SS;        // 516096
  const size_t RECON_OFF = ATTN_OFF + (size_t)BB * 15; // 516576

  // workspace layout (floats); all offsets multiple of 4 -> 16B aligned
  float* ws      = (float*)d_ws;
  float* partial = ws;                                    // 63*32*8064 = 16,257,024
  float* flat    = partial + (size_t)NCHUNK * BB * SS;    // 4,128,768
  float* mainT   = flat + (size_t)BB * DD * SS;           // 258,048  [s][b]
  float* m       = mainT + (size_t)BB * SS;               // 258,048  [b][s]
  float* scores  = m + (size_t)BB * SS;                   // 480

  // 1) fused conv+relu+recon+pool
  k12_conv_recon<<<dim3(BB * DD), dim3(256), 0, stream>>>(
      x, conv_w, conv_b, deconv_w, deconv_b, flat, mainT, out + RECON_OFF);

  // 2) big matmul partials
  k3_matmul<<<dim3(NCB, NCHUNK), dim3(256), 0, stream>>>(W_attn, mainT, partial);

  // 3) reduce -> m
  k3b_reduce<<<dim3((BB * SS / 4) / 256), dim3(256), 0, stream>>>(
      (const float4*)partial, (float4*)m);

  // 4) scores
  k4_scores<<<dim3(BB * 15), dim3(256), 0, stream>>>(m, flat, scores);

  // 5) softmax -> attn section of out
  k5_softmax<<<dim3(BB), dim3(64), 0, stream>>>(scores, out + ATTN_OFF);

  // 6) main copy + weighted
  k6_out<<<dim3((SS + 255) / 256, BB), dim3(256), 0, stream>>>(
      flat, out + ATTN_OFF, out);
}

// Round 12
// 163.219 us; speedup vs baseline: 1.1177x; 1.1177x over previous
//
#include <hip/hip_runtime.h>
#include <math.h>

#define BB 32
#define LL 256
#define DD 16
#define HH 64
#define KK 5
#define TT 252          // LL - KK + 1
#define PP 126          // TT/2
#define SS 8064         // HH*PP
#define NCHUNK 42
#define CHUNK 192       // 42*192 = 8064
#define NCB 16          // 16 blocks * 512 cols = 8192 >= 8064

// ---------------- kernel 12: conv + relu + recon + pool (fused per (b,d)) --
__global__ __launch_bounds__(256) void k12_conv_recon(
    const float* __restrict__ x, const float* __restrict__ cw,
    const float* __restrict__ cb, const float* __restrict__ dw,
    const float* __restrict__ db, float* __restrict__ flat,
    float* __restrict__ mainT, float* __restrict__ recon) {
  __shared__ float ylds[HH * TT];   // 64*252 = 16128 f = 64512 B
  __shared__ float xs[LL];
  __shared__ float cws[HH * KK];
  __shared__ float dws[HH * KK];
  __shared__ float cbs[HH];

  int bd = blockIdx.x;              // b*DD + d
  int b = bd / DD, d = bd % DD;
  int tid = threadIdx.x;

  xs[tid] = x[((size_t)b * LL + tid) * DD + d];
  for (int i = tid; i < HH * KK; i += 256) {
    cws[i] = cw[(size_t)d * HH * KK + i];
    dws[i] = dw[(size_t)d * HH * KK + i];
  }
  if (tid < HH) cbs[tid] = cb[d * HH + tid];
  __syncthreads();

  {
    int h = tid >> 2, a = tid & 3;
    int t0 = a * 63;
    float w0 = cws[h * KK + 0], w1 = cws[h * KK + 1], w2 = cws[h * KK + 2],
          w3 = cws[h * KK + 3], w4 = cws[h * KK + 4];
    float bias = cbs[h];
    float x0 = xs[t0], x1 = xs[t0 + 1], x2 = xs[t0 + 2], x3 = xs[t0 + 3],
          x4 = xs[t0 + 4];
    float* yrow = ylds + h * TT + t0;
    #pragma unroll 7
    for (int t = 0; t < 63; ++t) {
      float yv = fmaf(w4, x4, fmaf(w3, x3, fmaf(w2, x2, fmaf(w1, x1, fmaf(w0, x0, bias)))));
      yrow[t] = fmaxf(yv, 0.f);
      x0 = x1; x1 = x2; x2 = x3; x3 = x4;
      if (t < 62) x4 = xs[t0 + t + 5];
    }
  }
  __syncthreads();

  for (int i = tid; i < HH * PP; i += 256) {
    int h = i / PP, p = i - h * PP;
    float pooled = 0.5f * (ylds[h * TT + 2 * p] + ylds[h * TT + 2 * p + 1]);
    flat[(size_t)bd * SS + i] = pooled;
    if (d == 0) mainT[(size_t)i * BB + b] = pooled;   // [s][b]
  }

  {
    int l = tid;
    float acc = db[d];
    for (int h = 0; h < HH; ++h) {
      const float* yl = ylds + h * TT;
      #pragma unroll
      for (int j = 0; j < KK; ++j) {
        int t = l - j;
        if (t >= 0 && t < TT) acc = fmaf(yl[t], dws[h * KK + j], acc);
      }
    }
    recon[(size_t)bd * LL + l] = acc;
  }
}

// ---------------- kernel 3: partial = main @ W_attn -------------------------
// Thread tile = 8 batches x 8 cols (two dense 256-col halves).
// 16 NAMED float4 accumulators (64 VGPR) + 8 NAMED float4 W-prefetch (32) ->
// ~115 VGPR total, no spill (round-11 lesson: 32 accs = 160 regs = spill).
// Per k-step: 2 coalesced W dwordx4 (vmcnt, 4-step prefetch depth) +
// 2 uniform ds_read_b128 (lgkmcnt, 24KB LDS m-chunk) feed 64 FMA-instr (1:16).
#define FMA4V(A, WF, S)                                       \
  A.x = fmaf(WF.x, S, A.x); A.y = fmaf(WF.y, S, A.y);         \
  A.z = fmaf(WF.z, S, A.z); A.w = fmaf(WF.w, S, A.w);

// consume (P0,P1) for k-step KI, prefetch KI+4 into them, do 64 FMAs
#define KST(P0, P1, KI) {                                               \
  float4 w0 = P0, w1 = P1;                                              \
  if ((KI) + 4 < CHUNK) {                                               \
    P0 = *(const float4*)(wp0 + (size_t)((KI) + 4) * SS);               \
    P1 = *(const float4*)(wp1 + (size_t)((KI) + 4) * SS);               \
  }                                                                     \
  const float* mr = mlds + (KI) * BB + br * 8;                          \
  float4 q0 = *(const float4*)(mr), q1 = *(const float4*)(mr + 4);      \
  FMA4V(L0, w0, q0.x) FMA4V(L1, w0, q0.y) FMA4V(L2, w0, q0.z)           \
  FMA4V(L3, w0, q0.w) FMA4V(L4, w0, q1.x) FMA4V(L5, w0, q1.y)           \
  FMA4V(L6, w0, q1.z) FMA4V(L7, w0, q1.w)                               \
  FMA4V(H0, w1, q0.x) FMA4V(H1, w1, q0.y) FMA4V(H2, w1, q0.z)           \
  FMA4V(H3, w1, q0.w) FMA4V(H4, w1, q1.x) FMA4V(H5, w1, q1.y)           \
  FMA4V(H6, w1, q1.z) FMA4V(H7, w1, q1.w) }

__global__ __launch_bounds__(256) void k3_matmul(
    const float* __restrict__ W, const float* __restrict__ mainT,
    float* __restrict__ partial) {
  __shared__ float mlds[CHUNK * BB];   // 192*32*4 = 24 KB
  int chunk = blockIdx.y;
  int s0 = chunk * CHUNK;
  int tid = threadIdx.x;

  // stage m chunk (1536 float4 / 256 thr = 6 each, coalesced)
  {
    const float4* src = (const float4*)(mainT + (size_t)s0 * BB);
    float4* dst = (float4*)mlds;
    #pragma unroll
    for (int i = 0; i < 6; ++i) dst[tid + i * 256] = src[tid + i * 256];
  }
  __syncthreads();

  int br = tid >> 6;                         // 0..3 (wave-uniform), 8 batches
  int lane = tid & 63;
  int c0 = blockIdx.x * 512 + lane * 4;      // half0 col (max 7932, in range)
  int c1 = c0 + 256;                         // half1 col (may exceed SS)
  int c1l = c1 <= SS - 4 ? c1 : SS - 4;      // clamped load col

  float4 z = make_float4(0.f, 0.f, 0.f, 0.f);
  float4 L0 = z, L1 = z, L2 = z, L3 = z, L4 = z, L5 = z, L6 = z, L7 = z;
  float4 H0 = z, H1 = z, H2 = z, H3 = z, H4 = z, H5 = z, H6 = z, H7 = z;

  const float* wp0 = W + (size_t)s0 * SS + c0;
  const float* wp1 = W + (size_t)s0 * SS + c1l;

  // 4-step-deep W prefetch (pure vmcnt queue)
  float4 pA0 = *(const float4*)(wp0);
  float4 pA1 = *(const float4*)(wp1);
  float4 pB0 = *(const float4*)(wp0 + (size_t)SS);
  float4 pB1 = *(const float4*)(wp1 + (size_t)SS);
  float4 pC0 = *(const float4*)(wp0 + 2 * (size_t)SS);
  float4 pC1 = *(const float4*)(wp1 + 2 * (size_t)SS);
  float4 pD0 = *(const float4*)(wp0 + 3 * (size_t)SS);
  float4 pD1 = *(const float4*)(wp1 + 3 * (size_t)SS);

  #pragma unroll 1
  for (int k = 0; k < CHUNK; k += 4) {
    KST(pA0, pA1, k + 0)
    KST(pB0, pB1, k + 1)
    KST(pC0, pC1, k + 2)
    KST(pD0, pD1, k + 3)
  }

  {
    float* pp = partial + ((size_t)chunk * BB + br * 8) * SS + c0;
    *(float4*)(pp)                  = L0;
    *(float4*)(pp + 1 * (size_t)SS) = L1;
    *(float4*)(pp + 2 * (size_t)SS) = L2;
    *(float4*)(pp + 3 * (size_t)SS) = L3;
    *(float4*)(pp + 4 * (size_t)SS) = L4;
    *(float4*)(pp + 5 * (size_t)SS) = L5;
    *(float4*)(pp + 6 * (size_t)SS) = L6;
    *(float4*)(pp + 7 * (size_t)SS) = L7;
  }
  if (c1 < SS) {
    float* pp = partial + ((size_t)chunk * BB + br * 8) * SS + c1;
    *(float4*)(pp)                  = H0;
    *(float4*)(pp + 1 * (size_t)SS) = H1;
    *(float4*)(pp + 2 * (size_t)SS) = H2;
    *(float4*)(pp + 3 * (size_t)SS) = H3;
    *(float4*)(pp + 4 * (size_t)SS) = H4;
    *(float4*)(pp + 5 * (size_t)SS) = H5;
    *(float4*)(pp + 6 * (size_t)SS) = H6;
    *(float4*)(pp + 7 * (size_t)SS) = H7;
  }
}

// ---------------- kernel 3b: reduce partials -> m (float4) ------------------
__global__ __launch_bounds__(256) void k3b_reduce(
    const float4* __restrict__ partial, float4* __restrict__ m) {
  int i = blockIdx.x * 256 + threadIdx.x;      // < BB*SS/4 = 64512
  float4 s = make_float4(0.f, 0.f, 0.f, 0.f);
  for (int c = 0; c < NCHUNK; ++c) {
    float4 v = partial[(size_t)c * (BB * SS / 4) + i];
    s.x += v.x; s.y += v.y; s.z += v.z; s.w += v.w;
  }
  m[i] = s;
}

// ---------------- kernel 4: scores[b,d'] = <m[b,:], aux[b,d',:]> ------------
__global__ __launch_bounds__(256) void k4_scores(
    const float* __restrict__ m, const float* __restrict__ flat,
    float* __restrict__ scores) {
  int bd = blockIdx.x;            // b*15 + dd
  int b = bd / 15, dd = bd % 15;
  const float* mb = m + (size_t)b * SS;
  const float* ab = flat + ((size_t)b * DD + 1 + dd) * SS;
  float p = 0.f;
  for (int s = threadIdx.x; s < SS; s += 256) p = fmaf(mb[s], ab[s], p);
  #pragma unroll
  for (int o = 32; o; o >>= 1) p += __shfl_xor(p, o);
  __shared__ float red[4];
  if ((threadIdx.x & 63) == 0) red[threadIdx.x >> 6] = p;
  __syncthreads();
  if (threadIdx.x == 0) scores[bd] = red[0] + red[1] + red[2] + red[3];
}

// ---------------- kernel 5: softmax over 15 ---------------------------------
__global__ __launch_bounds__(64) void k5_softmax(
    const float* __restrict__ scores, float* __restrict__ attn_out) {
  int b = blockIdx.x;
  int lane = threadIdx.x;
  float v = (lane < 15) ? scores[b * 15 + lane] : -INFINITY;
  float mx = v;
  #pragma unroll
  for (int o = 32; o; o >>= 1) mx = fmaxf(mx, __shfl_xor(mx, o));
  float e = (lane < 15) ? expf(v - mx) : 0.f;
  float sum = e;
  #pragma unroll
  for (int o = 32; o; o >>= 1) sum += __shfl_xor(sum, o);
  if (lane < 15) attn_out[b * 15 + lane] = e / sum;
}

// ---------------- kernel 6: main copy + weighted sum ------------------------
__global__ __launch_bounds__(256) void k6_out(
    const float* __restrict__ flat, const float* __restrict__ attn,
    float* __restrict__ out) {
  int b = blockIdx.y;
  int s = blockIdx.x * 256 + threadIdx.x;
  if (s >= SS) return;
  const float* fb = flat + (size_t)b * DD * SS;
  out[(size_t)b * 2 * SS + s] = fb[s];
  float w = 0.f;
  #pragma unroll
  for (int d = 0; d < 15; ++d)
    w = fmaf(attn[b * 15 + d], fb[(size_t)(1 + d) * SS + s], w);
  out[(size_t)b * 2 * SS + SS + s] = w;
}

// ---------------------------------------------------------------------------
extern "C" void kernel_launch(void* const* d_in, const int* in_sizes, int n_in,
                              void* d_out, int out_size, void* d_ws, size_t ws_size,
                              hipStream_t stream) {
  const float* x        = (const float*)d_in[0];
  const float* conv_w   = (const float*)d_in[1];
  const float* conv_b   = (const float*)d_in[2];
  const float* deconv_w = (const float*)d_in[3];
  const float* deconv_b = (const float*)d_in[4];
  const float* W_attn   = (const float*)d_in[5];
  float* out = (float*)d_out;

  // output layout: [ out (516096) | attn (480) | recon (131072) ]
  const size_t ATTN_OFF  = (size_t)BB * 2 * SS;        // 516096
  const size_t RECON_OFF = ATTN_OFF + (size_t)BB * 15; // 516576

  // workspace layout (floats); all offsets multiple of 4 -> 16B aligned
  float* ws      = (float*)d_ws;
  float* partial = ws;                                    // 42*32*8064 = 10,838,016
  float* flat    = partial + (size_t)NCHUNK * BB * SS;    // 4,128,768
  float* mainT   = flat + (size_t)BB * DD * SS;           // 258,048  [s][b]
  float* m       = mainT + (size_t)BB * SS;               // 258,048  [b][s]
  float* scores  = m + (size_t)BB * SS;                   // 480

  // 1) fused conv+relu+recon+pool
  k12_conv_recon<<<dim3(BB * DD), dim3(256), 0, stream>>>(
      x, conv_w, conv_b, deconv_w, deconv_b, flat, mainT, out + RECON_OFF);

  // 2) big matmul partials
  k3_matmul<<<dim3(NCB, NCHUNK), dim3(256), 0, stream>>>(W_attn, mainT, partial);

  // 3) reduce -> m
  k3b_reduce<<<dim3((BB * SS / 4) / 256), dim3(256), 0, stream>>>(
      (const float4*)partial, (float4*)m);

  // 4) scores
  k4_scores<<<dim3(BB * 15), dim3(256), 0, stream>>>(m, flat, scores);

  // 5) softmax -> attn section of out
  k5_softmax<<<dim3(BB), dim3(64), 0, stream>>>(scores, out + ATTN_OFF);

  // 6) main copy + weighted
  k6_out<<<dim3((SS + 255) / 256, BB), dim3(256), 0, stream>>>(
      flat, out + ATTN_OFF, out);
}

// Round 13
// 106.745 us; speedup vs baseline: 1.7090x; 1.5291x over previous
//
#include <hip/hip_runtime.h>
#include <math.h>

#define BB 32
#define LL 256
#define DD 16
#define HH 64
#define KK 5
#define TT 252          // LL - KK + 1
#define PP 126          // TT/2
#define SS 8064         // HH*PP
#define NCHUNK 12
#define CHUNK 672       // 12*672 = 8064; 672 = 21*32
#define NKT 21          // K-tiles per chunk (KT=32)

typedef __attribute__((ext_vector_type(8))) short bf16x8;
typedef __attribute__((ext_vector_type(4))) float f32x4;

__device__ __forceinline__ unsigned short f2bf(float f) {
  unsigned int u = __float_as_uint(f);
  u += 0x7FFFu + ((u >> 16) & 1u);          // round-to-nearest-even
  return (unsigned short)(u >> 16);
}
__device__ __forceinline__ float bf2f(unsigned short h) {
  return __uint_as_float(((unsigned int)h) << 16);
}

// ---------------- kernel 12: conv + relu + recon + pool (fused per (b,d)) --
__global__ __launch_bounds__(256) void k12_conv_recon(
    const float* __restrict__ x, const float* __restrict__ cw,
    const float* __restrict__ cb, const float* __restrict__ dw,
    const float* __restrict__ db, float* __restrict__ flat,
    unsigned short* __restrict__ mainH, unsigned short* __restrict__ mainL,
    float* __restrict__ recon) {
  __shared__ float ylds[HH * TT];   // 64*252 = 16128 f = 64512 B
  __shared__ float xs[LL];
  __shared__ float cws[HH * KK];
  __shared__ float dws[HH * KK];
  __shared__ float cbs[HH];

  int bd = blockIdx.x;              // b*DD + d
  int b = bd / DD, d = bd % DD;
  int tid = threadIdx.x;

  xs[tid] = x[((size_t)b * LL + tid) * DD + d];
  for (int i = tid; i < HH * KK; i += 256) {
    cws[i] = cw[(size_t)d * HH * KK + i];
    dws[i] = dw[(size_t)d * HH * KK + i];
  }
  if (tid < HH) cbs[tid] = cb[d * HH + tid];
  __syncthreads();

  {
    int h = tid >> 2, a = tid & 3;
    int t0 = a * 63;
    float w0 = cws[h * KK + 0], w1 = cws[h * KK + 1], w2 = cws[h * KK + 2],
          w3 = cws[h * KK + 3], w4 = cws[h * KK + 4];
    float bias = cbs[h];
    float x0 = xs[t0], x1 = xs[t0 + 1], x2 = xs[t0 + 2], x3 = xs[t0 + 3],
          x4 = xs[t0 + 4];
    float* yrow = ylds + h * TT + t0;
    #pragma unroll 7
    for (int t = 0; t < 63; ++t) {
      float yv = fmaf(w4, x4, fmaf(w3, x3, fmaf(w2, x2, fmaf(w1, x1, fmaf(w0, x0, bias)))));
      yrow[t] = fmaxf(yv, 0.f);
      x0 = x1; x1 = x2; x2 = x3; x3 = x4;
      if (t < 62) x4 = xs[t0 + t + 5];
    }
  }
  __syncthreads();

  for (int i = tid; i < HH * PP; i += 256) {
    int h = i / PP, p = i - h * PP;
    float pooled = 0.5f * (ylds[h * TT + 2 * p] + ylds[h * TT + 2 * p + 1]);
    flat[(size_t)bd * SS + i] = pooled;
    if (d == 0) {
      unsigned short hb = f2bf(pooled);
      mainH[(size_t)b * SS + i] = hb;
      mainL[(size_t)b * SS + i] = f2bf(pooled - bf2f(hb));
    }
  }

  {
    int l = tid;
    float acc = db[d];
    for (int h = 0; h < HH; ++h) {
      const float* yl = ylds + h * TT;
      #pragma unroll
      for (int j = 0; j < KK; ++j) {
        int t = l - j;
        if (t >= 0 && t < TT) acc = fmaf(yl[t], dws[h * KK + j], acc);
      }
    }
    recon[(size_t)bd * LL + l] = acc;
  }
}

// ---------------- kernel 3: partial = main @ W_attn via bf16 hi/lo MFMA -----
// Block: 64 cols x 672 k-rows. Per K-tile (32k): stage W f32 -> bf16 hi/lo LDS
// + A (pre-split bf16) tile; 4 waves x {2 col-tiles x 3 mfma}.
// Fragment layouts (learn_hip m89-verified): A row=lane&15, k=(lane>>4)*8+e;
// B col=lane&15, k=(lane>>4)*8+e; D col=lane&15, row=(lane>>4)*4+reg.
__global__ __launch_bounds__(256) void k3_mfma(
    const float* __restrict__ W, const unsigned short* __restrict__ mainH,
    const unsigned short* __restrict__ mainL, float* __restrict__ partial) {
  __shared__ unsigned short AH[4 * 32 * 8];   // [g][b][e]  2 KB
  __shared__ unsigned short AL[4 * 32 * 8];
  __shared__ unsigned short BH[4 * 64 * 8];   // [g][c][e]  4 KB
  __shared__ unsigned short BL[4 * 64 * 8];

  int tid = threadIdx.x;
  int chunk = blockIdx.y;
  int s0 = chunk * CHUNK;
  int cb = blockIdx.x * 64;

  int lane = tid & 63;
  int wv = tid >> 6;
  int mr = wv & 1;              // row-tile (batches 16mr..16mr+15)
  int nt0 = (wv >> 1) * 2;      // first of two col-tiles

  f32x4 acc0 = {0.f, 0.f, 0.f, 0.f};
  f32x4 acc1 = {0.f, 0.f, 0.f, 0.f};

  int sc = tid & 63;            // staging col
  int sg = tid >> 6;            // staging k-octet (8 rows)

  // LDS read offsets (shorts)
  int aoff = (lane >> 4) * 256 + ((lane & 15) + 16 * mr) * 8;
  int b0off = (lane >> 4) * 512 + ((lane & 15) + 16 * nt0) * 8;
  int b1off = b0off + 16 * 8;

  #pragma unroll 1
  for (int kt = 0; kt < NKT; ++kt) {
    // ---- stage W 32x64 tile as hi/lo bf16 ----
    const float* wsrc = W + (size_t)(s0 + kt * 32 + sg * 8) * SS + cb + sc;
    bf16x8 vh, vl;
    #pragma unroll
    for (int j = 0; j < 8; ++j) {
      float f = wsrc[(size_t)j * SS];
      unsigned short h = f2bf(f);
      float rem = f - bf2f(h);
      vh[j] = (short)h;
      vl[j] = (short)f2bf(rem);
    }
    *(bf16x8*)&BH[sg * 512 + sc * 8] = vh;
    *(bf16x8*)&BL[sg * 512 + sc * 8] = vl;
    // ---- stage A 32x32 tile (already bf16 hi/lo in global) ----
    if (tid < 128) {
      int ab = tid >> 2;        // batch 0..31
      int aq = tid & 3;         // k-octet 0..3
      size_t off = (size_t)ab * SS + (size_t)(s0 + kt * 32 + aq * 8);
      *(bf16x8*)&AH[aq * 256 + ab * 8] = *(const bf16x8*)(mainH + off);
      *(bf16x8*)&AL[aq * 256 + ab * 8] = *(const bf16x8*)(mainL + off);
    }
    __syncthreads();
    // ---- MFMA ----
    bf16x8 ah = *(const bf16x8*)&AH[aoff];
    bf16x8 al = *(const bf16x8*)&AL[aoff];
    bf16x8 b0h = *(const bf16x8*)&BH[b0off];
    bf16x8 b0l = *(const bf16x8*)&BL[b0off];
    bf16x8 b1h = *(const bf16x8*)&BH[b1off];
    bf16x8 b1l = *(const bf16x8*)&BL[b1off];
    acc0 = __builtin_amdgcn_mfma_f32_16x16x32_bf16(ah, b0h, acc0, 0, 0, 0);
    acc0 = __builtin_amdgcn_mfma_f32_16x16x32_bf16(ah, b0l, acc0, 0, 0, 0);
    acc0 = __builtin_amdgcn_mfma_f32_16x16x32_bf16(al, b0h, acc0, 0, 0, 0);
    acc1 = __builtin_amdgcn_mfma_f32_16x16x32_bf16(ah, b1h, acc1, 0, 0, 0);
    acc1 = __builtin_amdgcn_mfma_f32_16x16x32_bf16(ah, b1l, acc1, 0, 0, 0);
    acc1 = __builtin_amdgcn_mfma_f32_16x16x32_bf16(al, b1h, acc1, 0, 0, 0);
    __syncthreads();
  }

  // ---- epilogue: D col=lane&15, row=(lane>>4)*4+reg ----
  int row0 = mr * 16 + (lane >> 4) * 4;
  int col0 = cb + nt0 * 16 + (lane & 15);
  float* pp = partial + ((size_t)chunk * BB + row0) * SS + col0;
  pp[0 * (size_t)SS] = acc0[0];
  pp[1 * (size_t)SS] = acc0[1];
  pp[2 * (size_t)SS] = acc0[2];
  pp[3 * (size_t)SS] = acc0[3];
  pp += 16;
  pp[0 * (size_t)SS] = acc1[0];
  pp[1 * (size_t)SS] = acc1[1];
  pp[2 * (size_t)SS] = acc1[2];
  pp[3 * (size_t)SS] = acc1[3];
}

// ---------------- kernel 3b: reduce partials -> m (float4) ------------------
__global__ __launch_bounds__(256) void k3b_reduce(
    const float4* __restrict__ partial, float4* __restrict__ m) {
  int i = blockIdx.x * 256 + threadIdx.x;      // < BB*SS/4 = 64512
  float4 s = make_float4(0.f, 0.f, 0.f, 0.f);
  #pragma unroll
  for (int c = 0; c < NCHUNK; ++c) {
    float4 v = partial[(size_t)c * (BB * SS / 4) + i];
    s.x += v.x; s.y += v.y; s.z += v.z; s.w += v.w;
  }
  m[i] = s;
}

// ---------------- kernel 4: scores[b,d'] = <m[b,:], aux[b,d',:]> ------------
__global__ __launch_bounds__(256) void k4_scores(
    const float* __restrict__ m, const float* __restrict__ flat,
    float* __restrict__ scores) {
  int bd = blockIdx.x;            // b*15 + dd
  int b = bd / 15, dd = bd % 15;
  const float* mb = m + (size_t)b * SS;
  const float* ab = flat + ((size_t)b * DD + 1 + dd) * SS;
  float p = 0.f;
  for (int s = threadIdx.x; s < SS; s += 256) p = fmaf(mb[s], ab[s], p);
  #pragma unroll
  for (int o = 32; o; o >>= 1) p += __shfl_xor(p, o);
  __shared__ float red[4];
  if ((threadIdx.x & 63) == 0) red[threadIdx.x >> 6] = p;
  __syncthreads();
  if (threadIdx.x == 0) scores[bd] = red[0] + red[1] + red[2] + red[3];
}

// ---------------- kernel 5: softmax over 15 ---------------------------------
__global__ __launch_bounds__(64) void k5_softmax(
    const float* __restrict__ scores, float* __restrict__ attn_out) {
  int b = blockIdx.x;
  int lane = threadIdx.x;
  float v = (lane < 15) ? scores[b * 15 + lane] : -INFINITY;
  float mx = v;
  #pragma unroll
  for (int o = 32; o; o >>= 1) mx = fmaxf(mx, __shfl_xor(mx, o));
  float e = (lane < 15) ? expf(v - mx) : 0.f;
  float sum = e;
  #pragma unroll
  for (int o = 32; o; o >>= 1) sum += __shfl_xor(sum, o);
  if (lane < 15) attn_out[b * 15 + lane] = e / sum;
}

// ---------------- kernel 6: main copy + weighted sum ------------------------
__global__ __launch_bounds__(256) void k6_out(
    const float* __restrict__ flat, const float* __restrict__ attn,
    float* __restrict__ out) {
  int b = blockIdx.y;
  int s = blockIdx.x * 256 + threadIdx.x;
  if (s >= SS) return;
  const float* fb = flat + (size_t)b * DD * SS;
  out[(size_t)b * 2 * SS + s] = fb[s];
  float w = 0.f;
  #pragma unroll
  for (int d = 0; d < 15; ++d)
    w = fmaf(attn[b * 15 + d], fb[(size_t)(1 + d) * SS + s], w);
  out[(size_t)b * 2 * SS + SS + s] = w;
}

// ---------------------------------------------------------------------------
extern "C" void kernel_launch(void* const* d_in, const int* in_sizes, int n_in,
                              void* d_out, int out_size, void* d_ws, size_t ws_size,
                              hipStream_t stream) {
  const float* x        = (const float*)d_in[0];
  const float* conv_w   = (const float*)d_in[1];
  const float* conv_b   = (const float*)d_in[2];
  const float* deconv_w = (const float*)d_in[3];
  const float* deconv_b = (const float*)d_in[4];
  const float* W_attn   = (const float*)d_in[5];
  float* out = (float*)d_out;

  // output layout: [ out (516096) | attn (480) | recon (131072) ]
  const size_t ATTN_OFF  = (size_t)BB * 2 * SS;        // 516096
  const size_t RECON_OFF = ATTN_OFF + (size_t)BB * 15; // 516576

  // workspace layout (floats / shorts); all 16B-aligned
  float* ws      = (float*)d_ws;
  float* partial = ws;                                        // 12*32*8064 = 3,096,576 f
  float* flat    = partial + (size_t)NCHUNK * BB * SS;        // 4,128,768 f
  unsigned short* mainH = (unsigned short*)(flat + (size_t)BB * DD * SS); // 258,048 u16
  unsigned short* mainL = mainH + (size_t)BB * SS;            // 258,048 u16
  float* m       = (float*)(mainL + (size_t)BB * SS);         // 258,048 f
  float* scores  = m + (size_t)BB * SS;                       // 480 f

  // 1) fused conv+relu+recon+pool (+ bf16 hi/lo split of main)
  k12_conv_recon<<<dim3(BB * DD), dim3(256), 0, stream>>>(
      x, conv_w, conv_b, deconv_w, deconv_b, flat, mainH, mainL, out + RECON_OFF);

  // 2) big matmul partials via MFMA
  k3_mfma<<<dim3(SS / 64, NCHUNK), dim3(256), 0, stream>>>(
      W_attn, mainH, mainL, partial);

  // 3) reduce -> m
  k3b_reduce<<<dim3((BB * SS / 4) / 256), dim3(256), 0, stream>>>(
      (const float4*)partial, (float4*)m);

  // 4) scores
  k4_scores<<<dim3(BB * 15), dim3(256), 0, stream>>>(m, flat, scores);

  // 5) softmax -> attn section of out
  k5_softmax<<<dim3(BB), dim3(64), 0, stream>>>(scores, out + ATTN_OFF);

  // 6) main copy + weighted
  k6_out<<<dim3((SS + 255) / 256, BB), dim3(256), 0, stream>>>(
      flat, out + ATTN_OFF, out);
}

// Round 14
// 100.971 us; speedup vs baseline: 1.8067x; 1.0572x over previous
//
#include <hip/hip_runtime.h>
#include <math.h>

#define BB 32
#define LL 256
#define DD 16
#define HH 64
#define KK 5
#define TT 252          // LL - KK + 1
#define PP 126          // TT/2
#define SS 8064         // HH*PP
#define NCHUNK 12
#define CHUNK 672       // 12*672 = 8064; 672 = 21*32
#define NKT 21          // K-tiles per chunk (KT=32)

typedef __attribute__((ext_vector_type(8))) short bf16x8;
typedef __attribute__((ext_vector_type(4))) float f32x4;

__device__ __forceinline__ unsigned short f2bf(float f) {
  unsigned int u = __float_as_uint(f);
  u += 0x7FFFu + ((u >> 16) & 1u);          // round-to-nearest-even
  return (unsigned short)(u >> 16);
}
__device__ __forceinline__ float bf2f(unsigned short h) {
  return __uint_as_float(((unsigned int)h) << 16);
}

// ---------------- kernel 12: conv + relu + recon + pool (fused per (b,d)) --
__global__ __launch_bounds__(256) void k12_conv_recon(
    const float* __restrict__ x, const float* __restrict__ cw,
    const float* __restrict__ cb, const float* __restrict__ dw,
    const float* __restrict__ db, float* __restrict__ flat,
    unsigned short* __restrict__ mainH, unsigned short* __restrict__ mainL,
    float* __restrict__ recon) {
  __shared__ float ylds[HH * TT];   // 64*252 = 16128 f = 64512 B
  __shared__ float xs[LL];
  __shared__ float cws[HH * KK];
  __shared__ float dws[HH * KK];
  __shared__ float cbs[HH];

  int bd = blockIdx.x;              // b*DD + d
  int b = bd / DD, d = bd % DD;
  int tid = threadIdx.x;

  xs[tid] = x[((size_t)b * LL + tid) * DD + d];
  for (int i = tid; i < HH * KK; i += 256) {
    cws[i] = cw[(size_t)d * HH * KK + i];
    dws[i] = dw[(size_t)d * HH * KK + i];
  }
  if (tid < HH) cbs[tid] = cb[d * HH + tid];
  __syncthreads();

  {
    int h = tid >> 2, a = tid & 3;
    int t0 = a * 63;
    float w0 = cws[h * KK + 0], w1 = cws[h * KK + 1], w2 = cws[h * KK + 2],
          w3 = cws[h * KK + 3], w4 = cws[h * KK + 4];
    float bias = cbs[h];
    float x0 = xs[t0], x1 = xs[t0 + 1], x2 = xs[t0 + 2], x3 = xs[t0 + 3],
          x4 = xs[t0 + 4];
    float* yrow = ylds + h * TT + t0;
    #pragma unroll 7
    for (int t = 0; t < 63; ++t) {
      float yv = fmaf(w4, x4, fmaf(w3, x3, fmaf(w2, x2, fmaf(w1, x1, fmaf(w0, x0, bias)))));
      yrow[t] = fmaxf(yv, 0.f);
      x0 = x1; x1 = x2; x2 = x3; x3 = x4;
      if (t < 62) x4 = xs[t0 + t + 5];
    }
  }
  __syncthreads();

  for (int i = tid; i < HH * PP; i += 256) {
    int h = i / PP, p = i - h * PP;
    float pooled = 0.5f * (ylds[h * TT + 2 * p] + ylds[h * TT + 2 * p + 1]);
    flat[(size_t)bd * SS + i] = pooled;
    if (d == 0) {
      unsigned short hb = f2bf(pooled);
      mainH[(size_t)b * SS + i] = hb;
      mainL[(size_t)b * SS + i] = f2bf(pooled - bf2f(hb));
    }
  }

  {
    int l = tid;
    float acc = db[d];
    for (int h = 0; h < HH; ++h) {
      const float* yl = ylds + h * TT;
      #pragma unroll
      for (int j = 0; j < KK; ++j) {
        int t = l - j;
        if (t >= 0 && t < TT) acc = fmaf(yl[t], dws[h * KK + j], acc);
      }
    }
    recon[(size_t)bd * LL + l] = acc;
  }
}

// ---------------- kernel 3: partial = main @ W_attn via bf16 hi/lo MFMA -----
// Software-pipelined: LDS double-buffered, ONE barrier per K-tile; W/A for
// tile kt+1 sit in registers while tile kt computes; loads for kt+2 issued
// before the barrier (plain reg loads ride vmcnt across it). W split uses
// truncation hi/lo (4 VALU/elem, err ~2^-16 rel — invisible vs 2^-9 floor).
// Fragment layouts identical to the round-13 kernel (verified passing).
__global__ __launch_bounds__(256) void k3_mfma(
    const float* __restrict__ W, const unsigned short* __restrict__ mainH,
    const unsigned short* __restrict__ mainL, float* __restrict__ partial) {
  __shared__ unsigned short AH[2][1024];   // [buf][aq*256 + ab*8]   2x2 KB
  __shared__ unsigned short AL[2][1024];
  __shared__ unsigned short BH[2][2048];   // [buf][sg*512 + sc*8]   2x4 KB
  __shared__ unsigned short BL[2][2048];

  int tid = threadIdx.x;
  int chunk = blockIdx.y;
  int s0 = chunk * CHUNK;
  int cbase = blockIdx.x * 64;

  int lane = tid & 63;
  int wv = tid >> 6;
  int mr = wv & 1;              // row-tile (batches 16mr..16mr+15)
  int nt0 = (wv >> 1) * 2;      // first of two col-tiles

  f32x4 acc0 = {0.f, 0.f, 0.f, 0.f};
  f32x4 acc1 = {0.f, 0.f, 0.f, 0.f};

  int sc = tid & 63;            // staging col
  int sg = tid >> 6;            // staging k-octet (8 rows)

  int aoff  = (lane >> 4) * 256 + ((lane & 15) + 16 * mr) * 8;
  int b0off = (lane >> 4) * 512 + ((lane & 15) + 16 * nt0) * 8;
  int b1off = b0off + 128;

  const float* wbase = W + (size_t)(s0 + sg * 8) * SS + cbase + sc;
  int ab = tid >> 2, aq = tid & 3;            // A staging (tid<128)
  size_t abase = (size_t)ab * SS + (size_t)(s0 + aq * 8);

  float f0, f1, f2, f3, f4, f5, f6, f7;       // raw W pipeline regs
  bf16x8 aHr, aLr;                            // A pipeline regs

#define LOADW(KT) {                                                   \
    const float* p_ = wbase + (size_t)(KT) * 32 * SS;                 \
    f0 = p_[0];                f1 = p_[(size_t)SS];                   \
    f2 = p_[2 * (size_t)SS];   f3 = p_[3 * (size_t)SS];               \
    f4 = p_[4 * (size_t)SS];   f5 = p_[5 * (size_t)SS];               \
    f6 = p_[6 * (size_t)SS];   f7 = p_[7 * (size_t)SS]; }

#define LOADA(KT) if (tid < 128) {                                    \
    aHr = *(const bf16x8*)(mainH + abase + (KT) * 32);                \
    aLr = *(const bf16x8*)(mainL + abase + (KT) * 32); }

#define SPLIT1(F, J) {                                                \
    unsigned int u_ = __float_as_uint(F);                             \
    vh[J] = (short)(u_ >> 16);                                        \
    float rem_ = F - __uint_as_float(u_ & 0xFFFF0000u);               \
    vl[J] = (short)(__float_as_uint(rem_) >> 16); }

#define CVTW(BUF) {                                                   \
    bf16x8 vh, vl;                                                    \
    SPLIT1(f0, 0) SPLIT1(f1, 1) SPLIT1(f2, 2) SPLIT1(f3, 3)           \
    SPLIT1(f4, 4) SPLIT1(f5, 5) SPLIT1(f6, 6) SPLIT1(f7, 7)           \
    *(bf16x8*)&BH[BUF][sg * 512 + sc * 8] = vh;                       \
    *(bf16x8*)&BL[BUF][sg * 512 + sc * 8] = vl; }

#define WRITEA(BUF) if (tid < 128) {                                  \
    *(bf16x8*)&AH[BUF][aq * 256 + ab * 8] = aHr;                      \
    *(bf16x8*)&AL[BUF][aq * 256 + ab * 8] = aLr; }

#define DOMFMA(BUF) {                                                 \
    bf16x8 ah  = *(const bf16x8*)&AH[BUF][aoff];                      \
    bf16x8 al  = *(const bf16x8*)&AL[BUF][aoff];                      \
    bf16x8 b0h = *(const bf16x8*)&BH[BUF][b0off];                     \
    bf16x8 b0l = *(const bf16x8*)&BL[BUF][b0off];                     \
    bf16x8 b1h = *(const bf16x8*)&BH[BUF][b1off];                     \
    bf16x8 b1l = *(const bf16x8*)&BL[BUF][b1off];                     \
    acc0 = __builtin_amdgcn_mfma_f32_16x16x32_bf16(ah, b0h, acc0, 0, 0, 0); \
    acc0 = __builtin_amdgcn_mfma_f32_16x16x32_bf16(ah, b0l, acc0, 0, 0, 0); \
    acc0 = __builtin_amdgcn_mfma_f32_16x16x32_bf16(al, b0h, acc0, 0, 0, 0); \
    acc1 = __builtin_amdgcn_mfma_f32_16x16x32_bf16(ah, b1h, acc1, 0, 0, 0); \
    acc1 = __builtin_amdgcn_mfma_f32_16x16x32_bf16(ah, b1l, acc1, 0, 0, 0); \
    acc1 = __builtin_amdgcn_mfma_f32_16x16x32_bf16(al, b1h, acc1, 0, 0, 0); }

  // prologue: tile0 -> buf0; tile1 -> regs
  LOADW(0) LOADA(0)
  CVTW(0) WRITEA(0)
  LOADW(1) LOADA(1)
  __syncthreads();

  #pragma unroll 1
  for (int kt = 0; kt < NKT; ++kt) {
    DOMFMA(kt & 1)
    if (kt + 1 < NKT) { CVTW((kt + 1) & 1) WRITEA((kt + 1) & 1) }
    if (kt + 2 < NKT) { LOADW(kt + 2) LOADA(kt + 2) }
    __syncthreads();
  }

  // epilogue: D col=lane&15, row=(lane>>4)*4+reg
  int row0 = mr * 16 + (lane >> 4) * 4;
  int col0 = cbase + nt0 * 16 + (lane & 15);
  float* pp = partial + ((size_t)chunk * BB + row0) * SS + col0;
  pp[0 * (size_t)SS] = acc0[0];
  pp[1 * (size_t)SS] = acc0[1];
  pp[2 * (size_t)SS] = acc0[2];
  pp[3 * (size_t)SS] = acc0[3];
  pp += 16;
  pp[0 * (size_t)SS] = acc1[0];
  pp[1 * (size_t)SS] = acc1[1];
  pp[2 * (size_t)SS] = acc1[2];
  pp[3 * (size_t)SS] = acc1[3];
#undef LOADW
#undef LOADA
#undef SPLIT1
#undef CVTW
#undef WRITEA
#undef DOMFMA
}

// ---------------- kernel 3b: reduce partials -> m (float4) ------------------
__global__ __launch_bounds__(256) void k3b_reduce(
    const float4* __restrict__ partial, float4* __restrict__ m) {
  int i = blockIdx.x * 256 + threadIdx.x;      // < BB*SS/4 = 64512
  float4 s = make_float4(0.f, 0.f, 0.f, 0.f);
  #pragma unroll
  for (int c = 0; c < NCHUNK; ++c) {
    float4 v = partial[(size_t)c * (BB * SS / 4) + i];
    s.x += v.x; s.y += v.y; s.z += v.z; s.w += v.w;
  }
  m[i] = s;
}

// ---------------- kernel 4: scores[b,d'] = <m[b,:], aux[b,d',:]> ------------
__global__ __launch_bounds__(256) void k4_scores(
    const float* __restrict__ m, const float* __restrict__ flat,
    float* __restrict__ scores) {
  int bd = blockIdx.x;            // b*15 + dd
  int b = bd / 15, dd = bd % 15;
  const float* mb = m + (size_t)b * SS;
  const float* ab = flat + ((size_t)b * DD + 1 + dd) * SS;
  float p = 0.f;
  for (int s = threadIdx.x; s < SS; s += 256) p = fmaf(mb[s], ab[s], p);
  #pragma unroll
  for (int o = 32; o; o >>= 1) p += __shfl_xor(p, o);
  __shared__ float red[4];
  if ((threadIdx.x & 63) == 0) red[threadIdx.x >> 6] = p;
  __syncthreads();
  if (threadIdx.x == 0) scores[bd] = red[0] + red[1] + red[2] + red[3];
}

// ---------------- kernel 5: softmax over 15 ---------------------------------
__global__ __launch_bounds__(64) void k5_softmax(
    const float* __restrict__ scores, float* __restrict__ attn_out) {
  int b = blockIdx.x;
  int lane = threadIdx.x;
  float v = (lane < 15) ? scores[b * 15 + lane] : -INFINITY;
  float mx = v;
  #pragma unroll
  for (int o = 32; o; o >>= 1) mx = fmaxf(mx, __shfl_xor(mx, o));
  float e = (lane < 15) ? expf(v - mx) : 0.f;
  float sum = e;
  #pragma unroll
  for (int o = 32; o; o >>= 1) sum += __shfl_xor(sum, o);
  if (lane < 15) attn_out[b * 15 + lane] = e / sum;
}

// ---------------- kernel 6: main copy + weighted sum ------------------------
__global__ __launch_bounds__(256) void k6_out(
    const float* __restrict__ flat, const float* __restrict__ attn,
    float* __restrict__ out) {
  int b = blockIdx.y;
  int s = blockIdx.x * 256 + threadIdx.x;
  if (s >= SS) return;
  const float* fb = flat + (size_t)b * DD * SS;
  out[(size_t)b * 2 * SS + s] = fb[s];
  float w = 0.f;
  #pragma unroll
  for (int d = 0; d < 15; ++d)
    w = fmaf(attn[b * 15 + d], fb[(size_t)(1 + d) * SS + s], w);
  out[(size_t)b * 2 * SS + SS + s] = w;
}

// ---------------------------------------------------------------------------
extern "C" void kernel_launch(void* const* d_in, const int* in_sizes, int n_in,
                              void* d_out, int out_size, void* d_ws, size_t ws_size,
                              hipStream_t stream) {
  const float* x        = (const float*)d_in[0];
  const float* conv_w   = (const float*)d_in[1];
  const float* conv_b   = (const float*)d_in[2];
  const float* deconv_w = (const float*)d_in[3];
  const float* deconv_b = (const float*)d_in[4];
  const float* W_attn   = (const float*)d_in[5];
  float* out = (float*)d_out;

  // output layout: [ out (516096) | attn (480) | recon (131072) ]
  const size_t ATTN_OFF  = (size_t)BB * 2 * SS;        // 516096
  const size_t RECON_OFF = ATTN_OFF + (size_t)BB * 15; // 516576

  // workspace layout; all 16B-aligned
  float* ws      = (float*)d_ws;
  float* partial = ws;                                        // 12*32*8064 f
  float* flat    = partial + (size_t)NCHUNK * BB * SS;        // 4,128,768 f
  unsigned short* mainH = (unsigned short*)(flat + (size_t)BB * DD * SS);
  unsigned short* mainL = mainH + (size_t)BB * SS;
  float* m       = (float*)(mainL + (size_t)BB * SS);
  float* scores  = m + (size_t)BB * SS;

  // 1) fused conv+relu+recon+pool (+ bf16 hi/lo split of main)
  k12_conv_recon<<<dim3(BB * DD), dim3(256), 0, stream>>>(
      x, conv_w, conv_b, deconv_w, deconv_b, flat, mainH, mainL, out + RECON_OFF);

  // 2) big matmul partials via MFMA (pipelined dbuf)
  k3_mfma<<<dim3(SS / 64, NCHUNK), dim3(256), 0, stream>>>(
      W_attn, mainH, mainL, partial);

  // 3) reduce -> m
  k3b_reduce<<<dim3((BB * SS / 4) / 256), dim3(256), 0, stream>>>(
      (const float4*)partial, (float4*)m);

  // 4) scores
  k4_scores<<<dim3(BB * 15), dim3(256), 0, stream>>>(m, flat, scores);

  // 5) softmax -> attn section of out
  k5_softmax<<<dim3(BB), dim3(64), 0, stream>>>(scores, out + ATTN_OFF);

  // 6) main copy + weighted
  k6_out<<<dim3((SS + 255) / 256, BB), dim3(256), 0, stream>>>(
      flat, out + ATTN_OFF, out);
}

// Round 15
// 97.977 us; speedup vs baseline: 1.8619x; 1.0306x over previous
//
#include <hip/hip_runtime.h>
#include <math.h>

#define BB 32
#define LL 256
#define DD 16
#define HH 64
#define KK 5
#define TT 252          // LL - KK + 1
#define PP 126          // TT/2
#define SS 8064         // HH*PP
#define NCHUNK 12
#define CHUNK 672       // 12*672 = 8064; 672 = 21*32
#define NKT 21          // K-tiles per chunk (KT=32)

typedef __attribute__((ext_vector_type(8))) short bf16x8;
typedef __attribute__((ext_vector_type(4))) float f32x4;

__device__ __forceinline__ unsigned short f2bf(float f) {
  unsigned int u = __float_as_uint(f);
  u += 0x7FFFu + ((u >> 16) & 1u);          // round-to-nearest-even
  return (unsigned short)(u >> 16);
}
__device__ __forceinline__ float bf2f(unsigned short h) {
  return __uint_as_float(((unsigned int)h) << 16);
}

// ---------------- kernel 12: conv + relu + recon + pool (fused per (b,d)) --
__global__ __launch_bounds__(256) void k12_conv_recon(
    const float* __restrict__ x, const float* __restrict__ cw,
    const float* __restrict__ cb, const float* __restrict__ dw,
    const float* __restrict__ db, float* __restrict__ flat,
    unsigned short* __restrict__ mainH, unsigned short* __restrict__ mainL,
    float* __restrict__ recon) {
  __shared__ float ylds[HH * TT];   // 64*252 = 16128 f = 64512 B
  __shared__ float xs[LL];
  __shared__ float cws[HH * KK];
  __shared__ float dws[HH * KK];
  __shared__ float cbs[HH];

  int bd = blockIdx.x;              // b*DD + d
  int b = bd / DD, d = bd % DD;
  int tid = threadIdx.x;

  xs[tid] = x[((size_t)b * LL + tid) * DD + d];
  for (int i = tid; i < HH * KK; i += 256) {
    cws[i] = cw[(size_t)d * HH * KK + i];
    dws[i] = dw[(size_t)d * HH * KK + i];
  }
  if (tid < HH) cbs[tid] = cb[d * HH + tid];
  __syncthreads();

  {
    int h = tid >> 2, a = tid & 3;
    int t0 = a * 63;
    float w0 = cws[h * KK + 0], w1 = cws[h * KK + 1], w2 = cws[h * KK + 2],
          w3 = cws[h * KK + 3], w4 = cws[h * KK + 4];
    float bias = cbs[h];
    float x0 = xs[t0], x1 = xs[t0 + 1], x2 = xs[t0 + 2], x3 = xs[t0 + 3],
          x4 = xs[t0 + 4];
    float* yrow = ylds + h * TT + t0;
    #pragma unroll 7
    for (int t = 0; t < 63; ++t) {
      float yv = fmaf(w4, x4, fmaf(w3, x3, fmaf(w2, x2, fmaf(w1, x1, fmaf(w0, x0, bias)))));
      yrow[t] = fmaxf(yv, 0.f);
      x0 = x1; x1 = x2; x2 = x3; x3 = x4;
      if (t < 62) x4 = xs[t0 + t + 5];
    }
  }
  __syncthreads();

  for (int i = tid; i < HH * PP; i += 256) {
    int h = i / PP, p = i - h * PP;
    float pooled = 0.5f * (ylds[h * TT + 2 * p] + ylds[h * TT + 2 * p + 1]);
    flat[(size_t)bd * SS + i] = pooled;
    if (d == 0) {
      unsigned short hb = f2bf(pooled);
      mainH[(size_t)b * SS + i] = hb;
      mainL[(size_t)b * SS + i] = f2bf(pooled - bf2f(hb));
    }
  }

  {
    int l = tid;
    float acc = db[d];
    for (int h = 0; h < HH; ++h) {
      const float* yl = ylds + h * TT;
      #pragma unroll
      for (int j = 0; j < KK; ++j) {
        int t = l - j;
        if (t >= 0 && t < TT) acc = fmaf(yl[t], dws[h * KK + j], acc);
      }
    }
    recon[(size_t)bd * LL + l] = acc;
  }
}

// ---------------- kernel 3: partial = main @ W_attn via bf16 hi/lo MFMA -----
// v11: loads issued at TOP of each iteration (max distance before the
// compiler's vmcnt(0)-drain at the barrier); dual named register sets
// (even/odd tile parity, loop unrolled x2); 128-col blocks (63x128 = SS
// exactly, no clamps), 1 barrier/K-tile. Fragment layouts unchanged from
// the verified round-13/14 kernel.
__global__ __launch_bounds__(256) void k3_mfma(
    const float* __restrict__ W, const unsigned short* __restrict__ mainH,
    const unsigned short* __restrict__ mainL, float* __restrict__ partial) {
  __shared__ unsigned short AH[2][1024];   // [buf][aq*256 + ab*8]   2x2 KB
  __shared__ unsigned short AL[2][1024];
  __shared__ unsigned short BH[2][4096];   // [buf][sg*1024 + c*8]   2x8 KB
  __shared__ unsigned short BL[2][4096];

  int tid = threadIdx.x;
  int chunk = blockIdx.y;
  int s0 = chunk * CHUNK;
  int cbase = blockIdx.x * 128;

  int lane = tid & 63;
  int wv = tid >> 6;
  int mr = wv & 1;              // row-tile (batches 16mr..16mr+15)
  int ctb = (wv >> 1) * 4;      // 4 col-tiles per wave

  f32x4 c0 = {0.f, 0.f, 0.f, 0.f};
  f32x4 c1 = {0.f, 0.f, 0.f, 0.f};
  f32x4 c2 = {0.f, 0.f, 0.f, 0.f};
  f32x4 c3 = {0.f, 0.f, 0.f, 0.f};

  int sc2 = (tid & 63) * 2;     // staging col pair
  int sg = tid >> 6;            // staging k-octet
  const float* wbase = W + (size_t)(s0 + sg * 8) * SS + cbase + sc2;

  int ab = tid >> 2, aq = tid & 3;            // A staging (tid<128)
  size_t abase = (size_t)ab * SS + (size_t)(s0 + aq * 8);

  int aoff  = (lane >> 4) * 256 + ((lane & 15) + 16 * mr) * 8;
  int boff0 = (lane >> 4) * 1024 + ((ctb) * 16 + (lane & 15)) * 8;
  // boff for ct = boff0 + ct*128

  // pipeline registers: even/odd tile sets
  float2 e0, e1, e2, e3, e4, e5, e6, e7;
  float2 o0, o1, o2, o3, o4, o5, o6, o7;
  bf16x8 aEH, aEL, aOH, aOL;

#define LOADW(R0,R1,R2,R3,R4,R5,R6,R7, KT) {                          \
    const float* p_ = wbase + (size_t)(KT) * 32 * SS;                 \
    R0 = *(const float2*)(p_);                                        \
    R1 = *(const float2*)(p_ + (size_t)SS);                           \
    R2 = *(const float2*)(p_ + 2 * (size_t)SS);                       \
    R3 = *(const float2*)(p_ + 3 * (size_t)SS);                       \
    R4 = *(const float2*)(p_ + 4 * (size_t)SS);                       \
    R5 = *(const float2*)(p_ + 5 * (size_t)SS);                       \
    R6 = *(const float2*)(p_ + 6 * (size_t)SS);                       \
    R7 = *(const float2*)(p_ + 7 * (size_t)SS); }

#define LOADA(RH, RL, KT) if (tid < 128) {                            \
    RH = *(const bf16x8*)(mainH + abase + (KT) * 32);                 \
    RL = *(const bf16x8*)(mainL + abase + (KT) * 32); }

#define SPLITC(F, J) {                                                \
    unsigned int ux_ = __float_as_uint(F.x);                          \
    unsigned int uy_ = __float_as_uint(F.y);                          \
    h0[J] = (short)(ux_ >> 16); h1[J] = (short)(uy_ >> 16);           \
    float rx_ = F.x - __uint_as_float(ux_ & 0xFFFF0000u);             \
    float ry_ = F.y - __uint_as_float(uy_ & 0xFFFF0000u);             \
    l0[J] = (short)(__float_as_uint(rx_) >> 16);                      \
    l1[J] = (short)(__float_as_uint(ry_) >> 16); }

#define CVTW(R0,R1,R2,R3,R4,R5,R6,R7, BUF) {                          \
    bf16x8 h0, h1, l0, l1;                                            \
    SPLITC(R0, 0) SPLITC(R1, 1) SPLITC(R2, 2) SPLITC(R3, 3)           \
    SPLITC(R4, 4) SPLITC(R5, 5) SPLITC(R6, 6) SPLITC(R7, 7)           \
    *(bf16x8*)&BH[BUF][sg * 1024 + sc2 * 8]     = h0;                 \
    *(bf16x8*)&BH[BUF][sg * 1024 + sc2 * 8 + 8] = h1;                 \
    *(bf16x8*)&BL[BUF][sg * 1024 + sc2 * 8]     = l0;                 \
    *(bf16x8*)&BL[BUF][sg * 1024 + sc2 * 8 + 8] = l1; }

#define WRITEA(RH, RL, BUF) if (tid < 128) {                          \
    *(bf16x8*)&AH[BUF][aq * 256 + ab * 8] = RH;                       \
    *(bf16x8*)&AL[BUF][aq * 256 + ab * 8] = RL; }

#define DOMFMA(BUF) {                                                 \
    bf16x8 ah  = *(const bf16x8*)&AH[BUF][aoff];                      \
    bf16x8 al  = *(const bf16x8*)&AL[BUF][aoff];                      \
    bf16x8 bh0 = *(const bf16x8*)&BH[BUF][boff0];                     \
    bf16x8 bl0 = *(const bf16x8*)&BL[BUF][boff0];                     \
    bf16x8 bh1 = *(const bf16x8*)&BH[BUF][boff0 + 128];               \
    bf16x8 bl1 = *(const bf16x8*)&BL[BUF][boff0 + 128];               \
    bf16x8 bh2 = *(const bf16x8*)&BH[BUF][boff0 + 256];               \
    bf16x8 bl2 = *(const bf16x8*)&BL[BUF][boff0 + 256];               \
    bf16x8 bh3 = *(const bf16x8*)&BH[BUF][boff0 + 384];               \
    bf16x8 bl3 = *(const bf16x8*)&BL[BUF][boff0 + 384];               \
    c0 = __builtin_amdgcn_mfma_f32_16x16x32_bf16(ah, bh0, c0, 0, 0, 0); \
    c0 = __builtin_amdgcn_mfma_f32_16x16x32_bf16(ah, bl0, c0, 0, 0, 0); \
    c0 = __builtin_amdgcn_mfma_f32_16x16x32_bf16(al, bh0, c0, 0, 0, 0); \
    c1 = __builtin_amdgcn_mfma_f32_16x16x32_bf16(ah, bh1, c1, 0, 0, 0); \
    c1 = __builtin_amdgcn_mfma_f32_16x16x32_bf16(ah, bl1, c1, 0, 0, 0); \
    c1 = __builtin_amdgcn_mfma_f32_16x16x32_bf16(al, bh1, c1, 0, 0, 0); \
    c2 = __builtin_amdgcn_mfma_f32_16x16x32_bf16(ah, bh2, c2, 0, 0, 0); \
    c2 = __builtin_amdgcn_mfma_f32_16x16x32_bf16(ah, bl2, c2, 0, 0, 0); \
    c2 = __builtin_amdgcn_mfma_f32_16x16x32_bf16(al, bh2, c2, 0, 0, 0); \
    c3 = __builtin_amdgcn_mfma_f32_16x16x32_bf16(ah, bh3, c3, 0, 0, 0); \
    c3 = __builtin_amdgcn_mfma_f32_16x16x32_bf16(ah, bl3, c3, 0, 0, 0); \
    c3 = __builtin_amdgcn_mfma_f32_16x16x32_bf16(al, bh3, c3, 0, 0, 0); }

  // prologue: tile0 -> buf0 (via even regs); tile1 -> odd regs
  LOADW(e0,e1,e2,e3,e4,e5,e6,e7, 0) LOADA(aEH, aEL, 0)
  CVTW(e0,e1,e2,e3,e4,e5,e6,e7, 0) WRITEA(aEH, aEL, 0)
  LOADW(o0,o1,o2,o3,o4,o5,o6,o7, 1) LOADA(aOH, aOL, 1)
  __syncthreads();

  #pragma unroll 1
  for (int kt = 0; kt < NKT - 1; kt += 2) {
    // even iteration kt: loads FIRST (max in-flight distance before barrier)
    LOADW(e0,e1,e2,e3,e4,e5,e6,e7, kt + 2) LOADA(aEH, aEL, kt + 2)
    DOMFMA(0)
    CVTW(o0,o1,o2,o3,o4,o5,o6,o7, 1) WRITEA(aOH, aOL, 1)
    __syncthreads();
    // odd iteration kt+1
    if (kt + 3 < NKT) {
      LOADW(o0,o1,o2,o3,o4,o5,o6,o7, kt + 3) LOADA(aOH, aOL, kt + 3)
    }
    DOMFMA(1)
    CVTW(e0,e1,e2,e3,e4,e5,e6,e7, 0) WRITEA(aEH, aEL, 0)
    __syncthreads();
  }
  DOMFMA(0)   // tail tile NKT-1 = 20 (even buf)

  // epilogue: D col=lane&15, row=(lane>>4)*4+reg
  int row0 = mr * 16 + (lane >> 4) * 4;
  int col0 = cbase + ctb * 16 + (lane & 15);
  float* pp = partial + ((size_t)chunk * BB + row0) * SS + col0;
  #pragma unroll
  for (int r = 0; r < 4; ++r) pp[(size_t)r * SS]      = c0[r];
  #pragma unroll
  for (int r = 0; r < 4; ++r) pp[(size_t)r * SS + 16] = c1[r];
  #pragma unroll
  for (int r = 0; r < 4; ++r) pp[(size_t)r * SS + 32] = c2[r];
  #pragma unroll
  for (int r = 0; r < 4; ++r) pp[(size_t)r * SS + 48] = c3[r];
#undef LOADW
#undef LOADA
#undef SPLITC
#undef CVTW
#undef WRITEA
#undef DOMFMA
}

// ---------------- kernel 3b: reduce partials -> m (float4) ------------------
__global__ __launch_bounds__(256) void k3b_reduce(
    const float4* __restrict__ partial, float4* __restrict__ m) {
  int i = blockIdx.x * 256 + threadIdx.x;      // < BB*SS/4 = 64512
  float4 s = make_float4(0.f, 0.f, 0.f, 0.f);
  #pragma unroll
  for (int c = 0; c < NCHUNK; ++c) {
    float4 v = partial[(size_t)c * (BB * SS / 4) + i];
    s.x += v.x; s.y += v.y; s.z += v.z; s.w += v.w;
  }
  m[i] = s;
}

// ---------------- kernel 4: scores[b,d'] = <m[b,:], aux[b,d',:]> ------------
__global__ __launch_bounds__(256) void k4_scores(
    const float* __restrict__ m, const float* __restrict__ flat,
    float* __restrict__ scores) {
  int bd = blockIdx.x;            // b*15 + dd
  int b = bd / 15, dd = bd % 15;
  const float* mb = m + (size_t)b * SS;
  const float* ab = flat + ((size_t)b * DD + 1 + dd) * SS;
  float p = 0.f;
  for (int s = threadIdx.x; s < SS; s += 256) p = fmaf(mb[s], ab[s], p);
  #pragma unroll
  for (int o = 32; o; o >>= 1) p += __shfl_xor(p, o);
  __shared__ float red[4];
  if ((threadIdx.x & 63) == 0) red[threadIdx.x >> 6] = p;
  __syncthreads();
  if (threadIdx.x == 0) scores[bd] = red[0] + red[1] + red[2] + red[3];
}

// ---------------- kernel 5: softmax over 15 ---------------------------------
__global__ __launch_bounds__(64) void k5_softmax(
    const float* __restrict__ scores, float* __restrict__ attn_out) {
  int b = blockIdx.x;
  int lane = threadIdx.x;
  float v = (lane < 15) ? scores[b * 15 + lane] : -INFINITY;
  float mx = v;
  #pragma unroll
  for (int o = 32; o; o >>= 1) mx = fmaxf(mx, __shfl_xor(mx, o));
  float e = (lane < 15) ? expf(v - mx) : 0.f;
  float sum = e;
  #pragma unroll
  for (int o = 32; o; o >>= 1) sum += __shfl_xor(sum, o);
  if (lane < 15) attn_out[b * 15 + lane] = e / sum;
}

// ---------------- kernel 6: main copy + weighted sum ------------------------
__global__ __launch_bounds__(256) void k6_out(
    const float* __restrict__ flat, const float* __restrict__ attn,
    float* __restrict__ out) {
  int b = blockIdx.y;
  int s = blockIdx.x * 256 + threadIdx.x;
  if (s >= SS) return;
  const float* fb = flat + (size_t)b * DD * SS;
  out[(size_t)b * 2 * SS + s] = fb[s];
  float w = 0.f;
  #pragma unroll
  for (int d = 0; d < 15; ++d)
    w = fmaf(attn[b * 15 + d], fb[(size_t)(1 + d) * SS + s], w);
  out[(size_t)b * 2 * SS + SS + s] = w;
}

// ---------------------------------------------------------------------------
extern "C" void kernel_launch(void* const* d_in, const int* in_sizes, int n_in,
                              void* d_out, int out_size, void* d_ws, size_t ws_size,
                              hipStream_t stream) {
  const float* x        = (const float*)d_in[0];
  const float* conv_w   = (const float*)d_in[1];
  const float* conv_b   = (const float*)d_in[2];
  const float* deconv_w = (const float*)d_in[3];
  const float* deconv_b = (const float*)d_in[4];
  const float* W_attn   = (const float*)d_in[5];
  float* out = (float*)d_out;

  // output layout: [ out (516096) | attn (480) | recon (131072) ]
  const size_t ATTN_OFF  = (size_t)BB * 2 * SS;        // 516096
  const size_t RECON_OFF = ATTN_OFF + (size_t)BB * 15; // 516576

  // workspace layout; all 16B-aligned
  float* ws      = (float*)d_ws;
  float* partial = ws;                                        // 12*32*8064 f
  float* flat    = partial + (size_t)NCHUNK * BB * SS;        // 4,128,768 f
  unsigned short* mainH = (unsigned short*)(flat + (size_t)BB * DD * SS);
  unsigned short* mainL = mainH + (size_t)BB * SS;
  float* m       = (float*)(mainL + (size_t)BB * SS);
  float* scores  = m + (size_t)BB * SS;

  // 1) fused conv+relu+recon+pool (+ bf16 hi/lo split of main)
  k12_conv_recon<<<dim3(BB * DD), dim3(256), 0, stream>>>(
      x, conv_w, conv_b, deconv_w, deconv_b, flat, mainH, mainL, out + RECON_OFF);

  // 2) big matmul partials via MFMA (load-early pipelined dbuf, 128-col blocks)
  k3_mfma<<<dim3(SS / 128, NCHUNK), dim3(256), 0, stream>>>(
      W_attn, mainH, mainL, partial);

  // 3) reduce -> m
  k3b_reduce<<<dim3((BB * SS / 4) / 256), dim3(256), 0, stream>>>(
      (const float4*)partial, (float4*)m);

  // 4) scores
  k4_scores<<<dim3(BB * 15), dim3(256), 0, stream>>>(m, flat, scores);

  // 5) softmax -> attn section of out
  k5_softmax<<<dim3(BB), dim3(64), 0, stream>>>(scores, out + ATTN_OFF);

  // 6) main copy + weighted
  k6_out<<<dim3((SS + 255) / 256, BB), dim3(256), 0, stream>>>(
      flat, out + ATTN_OFF, out);
}